// Round 2
// baseline (20324.590 us; speedup 1.0000x reference)
//
#include <hip/hip_runtime.h>

#define N_USERS 100000
#define N_ITEMS 50000
#define N_NODES 150000
#define EMBED_DIM 64

// ---------------------------------------------------------------------------
// init: x = acc = concat(user_embedding, item_embedding), vectorized float4
// ---------------------------------------------------------------------------
__global__ void init4_kernel(const float4* __restrict__ user,
                             const float4* __restrict__ item,
                             float4* __restrict__ x,
                             float4* __restrict__ acc,
                             int n_user4, int total4) {
    int i = blockIdx.x * blockDim.x + threadIdx.x;
    if (i < total4) {
        float4 v = (i < n_user4) ? user[i] : item[i - n_user4];
        x[i] = v;
        acc[i] = v;
    }
}

// ---------------------------------------------------------------------------
// scatter SpMM: 16 threads per edge, each handles 4 consecutive d (float4)
// y[row] += val * x[col]
// ---------------------------------------------------------------------------
__global__ void spmm_scatter_kernel(const int* __restrict__ rows,
                                    const int* __restrict__ cols,
                                    const float* __restrict__ vals,
                                    const float4* __restrict__ x4,
                                    float* __restrict__ y,
                                    int nnz) {
    unsigned int gid = blockIdx.x * blockDim.x + threadIdx.x;
    unsigned int e = gid >> 4;          // edge index
    if (e >= (unsigned int)nnz) return;
    unsigned int d4 = gid & 15u;        // which float4 chunk of the 64-dim row

    int r = rows[e];
    int c = cols[e];
    float v = vals[e];

    float4 xv = x4[(size_t)c * 16 + d4];
    float* yp = y + (size_t)r * EMBED_DIM + d4 * 4;
    atomicAdd(yp + 0, v * xv.x);
    atomicAdd(yp + 1, v * xv.y);
    atomicAdd(yp + 2, v * xv.z);
    atomicAdd(yp + 3, v * xv.w);
}

// ---------------------------------------------------------------------------
// acc += y, optionally scaled (final layer: (acc + y) * 0.25)
// ---------------------------------------------------------------------------
__global__ void acc4_kernel(float4* __restrict__ acc,
                            const float4* __restrict__ y,
                            int total4, float scale) {
    int i = blockIdx.x * blockDim.x + threadIdx.x;
    if (i < total4) {
        float4 a = acc[i];
        float4 b = y[i];
        a.x = (a.x + b.x) * scale;
        a.y = (a.y + b.y) * scale;
        a.z = (a.z + b.z) * scale;
        a.w = (a.w + b.w) * scale;
        acc[i] = a;
    }
}

extern "C" void kernel_launch(void* const* d_in, const int* in_sizes, int n_in,
                              void* d_out, int out_size, void* d_ws, size_t ws_size,
                              hipStream_t stream) {
    const float* user = (const float*)d_in[0];
    const float* item = (const float*)d_in[1];
    const int*   rows = (const int*)d_in[2];
    const int*   cols = (const int*)d_in[3];
    const float* vals = (const float*)d_in[4];
    float* out = (float*)d_out;

    const int nnz = in_sizes[2];
    const size_t nfloats = (size_t)N_NODES * EMBED_DIM;   // 9.6M floats
    const int total4 = (int)(nfloats / 4);                // 2.4M float4
    const int n_user4 = (N_USERS * EMBED_DIM) / 4;

    float* bufA = (float*)d_ws;
    float* bufB = bufA + nfloats;

    // x = acc = emb0
    {
        int blocks = (total4 + 255) / 256;
        init4_kernel<<<blocks, 256, 0, stream>>>(
            (const float4*)user, (const float4*)item,
            (float4*)bufA, (float4*)out, n_user4, total4);
    }

    float* x = bufA;
    float* y = bufB;
    for (int layer = 0; layer < 3; ++layer) {
        hipMemsetAsync(y, 0, nfloats * sizeof(float), stream);

        unsigned int threads = (unsigned int)nnz * 16u;   // 128M
        unsigned int blocks = (threads + 255u) / 256u;
        spmm_scatter_kernel<<<blocks, 256, 0, stream>>>(
            rows, cols, vals, (const float4*)x, y, nnz);

        float scale = (layer == 2) ? 0.25f : 1.0f;
        int ablocks = (total4 + 255) / 256;
        acc4_kernel<<<ablocks, 256, 0, stream>>>(
            (float4*)out, (const float4*)y, total4, scale);

        float* t = x; x = y; y = t;
    }
}

// Round 6
// 2262.332 us; speedup vs baseline: 8.9839x; 8.9839x over previous
//
#include <hip/hip_runtime.h>

#define N_USERS 100000
#define N_ITEMS 50000
#define N_NODES 150000
#define EMBED_DIM 64

// ===========================================================================
// Shared elementwise kernels
// ===========================================================================
__global__ void init4_kernel(const float4* __restrict__ user,
                             const float4* __restrict__ item,
                             float4* __restrict__ x,
                             float4* __restrict__ acc,
                             int n_user4, int total4) {
    int i = blockIdx.x * blockDim.x + threadIdx.x;
    if (i < total4) {
        float4 v = (i < n_user4) ? user[i] : item[i - n_user4];
        x[i] = v;
        acc[i] = v;
    }
}

// ===========================================================================
// CSR build: histogram -> exclusive scan (3-kernel hierarchical) -> scatter
// ===========================================================================
__global__ void hist_kernel(const int* __restrict__ rows, int* __restrict__ cnt, int nnz) {
    int e = blockIdx.x * blockDim.x + threadIdx.x;
    if (e < nnz) atomicAdd(&cnt[rows[e]], 1);
}

// 1024 items per block (256 thr x 4)
__global__ void block_sum_kernel(const int* __restrict__ cnt, int* __restrict__ bsum, int n) {
    __shared__ int lds[256];
    int tid = threadIdx.x;
    int base = blockIdx.x * 1024 + tid * 4;
    int s = 0;
#pragma unroll
    for (int j = 0; j < 4; ++j) { int idx = base + j; if (idx < n) s += cnt[idx]; }
    lds[tid] = s; __syncthreads();
    for (int off = 128; off > 0; off >>= 1) {
        if (tid < off) lds[tid] += lds[tid + off];
        __syncthreads();
    }
    if (tid == 0) bsum[blockIdx.x] = lds[0];
}

// single block, nb <= 256: exclusive scan of bsum in place
__global__ void scan_bsum_kernel(int* __restrict__ bsum, int nb) {
    __shared__ int lds[256];
    int tid = threadIdx.x;
    int v = (tid < nb) ? bsum[tid] : 0;
    lds[tid] = v; __syncthreads();
    for (int off = 1; off < 256; off <<= 1) {
        int t = (tid >= off) ? lds[tid - off] : 0;
        __syncthreads();
        lds[tid] += t;
        __syncthreads();
    }
    if (tid < nb) bsum[tid] = lds[tid] - v;   // exclusive
}

__global__ void scan_write_kernel(const int* __restrict__ cnt, const int* __restrict__ bsum,
                                  int* __restrict__ row_ptr, int n, int nnz) {
    __shared__ int lds[256];
    int tid = threadIdx.x;
    int base = blockIdx.x * 1024 + tid * 4;
    int v[4]; int s = 0;
#pragma unroll
    for (int j = 0; j < 4; ++j) { int idx = base + j; v[j] = (idx < n) ? cnt[idx] : 0; s += v[j]; }
    lds[tid] = s; __syncthreads();
    for (int off = 1; off < 256; off <<= 1) {
        int t = (tid >= off) ? lds[tid - off] : 0;
        __syncthreads();
        lds[tid] += t;
        __syncthreads();
    }
    int run = lds[tid] - s + bsum[blockIdx.x];  // exclusive prefix for this thread
#pragma unroll
    for (int j = 0; j < 4; ++j) {
        int idx = base + j;
        if (idx < n) row_ptr[idx] = run;
        run += v[j];
    }
    if (blockIdx.x == 0 && tid == 0) row_ptr[n] = nnz;
}

__global__ void csr_scatter_kernel(const int* __restrict__ rows, const int* __restrict__ cols,
                                   const float* __restrict__ vals,
                                   const int* __restrict__ row_ptr, int* __restrict__ row_off,
                                   int* __restrict__ scol, float* __restrict__ sval, int nnz) {
    int e = blockIdx.x * blockDim.x + threadIdx.x;
    if (e >= nnz) return;
    int r = rows[e];
    int idx = row_ptr[r] + atomicAdd(&row_off[r], 1);
    scol[idx] = cols[e];
    sval[idx] = vals[e];
}

// ===========================================================================
// Row-parallel gather SpMM: one wave (64 lanes) per row, lane = dim.
// y[r][lane] = sum_e val_e * x[col_e][lane];  out[r][lane] (+)= y, scaled at end
// ===========================================================================
__global__ __launch_bounds__(256) void spmm_csr_kernel(
        const int* __restrict__ row_ptr, const int* __restrict__ scol,
        const float* __restrict__ sval, const float* __restrict__ x,
        float* __restrict__ y, float* __restrict__ out, float final_scale) {
    int wid = (blockIdx.x * blockDim.x + threadIdx.x) >> 6;   // wave id = row
    int lane = threadIdx.x & 63;
    if (wid >= N_NODES) return;

    int start = row_ptr[wid];
    int end = row_ptr[wid + 1];
    float acc = 0.0f;

    for (int base = start; base < end; base += 64) {
        int e = base + lane;
        int c = 0; float v = 0.0f;
        if (e < end) { c = scol[e]; v = sval[e]; }
        int m = end - base; if (m > 64) m = 64;
        if (m == 64) {
#pragma unroll 8
            for (int j = 0; j < 64; ++j) {
                int cj = __shfl(c, j, 64);
                float vj = __shfl(v, j, 64);
                acc += vj * x[cj * EMBED_DIM + lane];
            }
        } else {
            for (int j = 0; j < m; ++j) {
                int cj = __shfl(c, j, 64);
                float vj = __shfl(v, j, 64);
                acc += vj * x[cj * EMBED_DIM + lane];
            }
        }
    }

    int o = wid * EMBED_DIM + lane;
    y[o] = acc;
    if (final_scale != 1.0f)
        out[o] = (out[o] + acc) * final_scale;
    else
        out[o] = out[o] + acc;
}

// ===========================================================================
// Fallback (ws too small): round-0 atomic scatter path
// ===========================================================================
__global__ void spmm_scatter_kernel(const int* __restrict__ rows, const int* __restrict__ cols,
                                    const float* __restrict__ vals, const float4* __restrict__ x4,
                                    float* __restrict__ y, int nnz) {
    unsigned int gid = blockIdx.x * blockDim.x + threadIdx.x;
    unsigned int e = gid >> 4;
    if (e >= (unsigned int)nnz) return;
    unsigned int d4 = gid & 15u;
    int r = rows[e]; int c = cols[e]; float v = vals[e];
    float4 xv = x4[(size_t)c * 16 + d4];
    float* yp = y + (size_t)r * EMBED_DIM + d4 * 4;
    atomicAdd(yp + 0, v * xv.x);
    atomicAdd(yp + 1, v * xv.y);
    atomicAdd(yp + 2, v * xv.z);
    atomicAdd(yp + 3, v * xv.w);
}

__global__ void acc4_kernel(float4* __restrict__ acc, const float4* __restrict__ y,
                            int total4, float scale) {
    int i = blockIdx.x * blockDim.x + threadIdx.x;
    if (i < total4) {
        float4 a = acc[i]; float4 b = y[i];
        a.x = (a.x + b.x) * scale; a.y = (a.y + b.y) * scale;
        a.z = (a.z + b.z) * scale; a.w = (a.w + b.w) * scale;
        acc[i] = a;
    }
}

// ===========================================================================
extern "C" void kernel_launch(void* const* d_in, const int* in_sizes, int n_in,
                              void* d_out, int out_size, void* d_ws, size_t ws_size,
                              hipStream_t stream) {
    const float* user = (const float*)d_in[0];
    const float* item = (const float*)d_in[1];
    const int*   rows = (const int*)d_in[2];
    const int*   cols = (const int*)d_in[3];
    const float* vals = (const float*)d_in[4];
    float* out = (float*)d_out;

    const int nnz = in_sizes[2];
    const size_t nfloats = (size_t)N_NODES * EMBED_DIM;   // 9.6M
    const int total4 = (int)(nfloats / 4);
    const int n_user4 = (N_USERS * EMBED_DIM) / 4;

    // ---- workspace layout (256B-aligned regions) ----
    char* ws = (char*)d_ws;
    size_t off = 0;
    auto alloc = [&](size_t bytes) { size_t p = off; off += (bytes + 255) & ~(size_t)255; return p; };
    size_t o_bufA  = alloc(nfloats * sizeof(float));
    size_t o_bufB  = alloc(nfloats * sizeof(float));
    size_t o_rptr  = alloc((N_NODES + 1) * sizeof(int));
    size_t o_roff  = alloc(N_NODES * sizeof(int));
    size_t o_bsum  = alloc(256 * sizeof(int));
    size_t o_scol  = alloc((size_t)nnz * sizeof(int));
    size_t o_sval  = alloc((size_t)nnz * sizeof(float));
    bool csr_ok = off <= ws_size;

    float* bufA = (float*)(ws + o_bufA);
    float* bufB = (float*)(ws + o_bufB);

    if (csr_ok) {
        int* row_ptr = (int*)(ws + o_rptr);
        int* row_off = (int*)(ws + o_roff);
        int* bsum    = (int*)(ws + o_bsum);
        int* scol    = (int*)(ws + o_scol);
        float* sval  = (float*)(ws + o_sval);

        // 1. histogram
        hipMemsetAsync(row_off, 0, N_NODES * sizeof(int), stream);
        int eblocks = (nnz + 255) / 256;
        hist_kernel<<<eblocks, 256, 0, stream>>>(rows, row_off, nnz);

        // 2. exclusive scan -> row_ptr
        int nscan = (N_NODES + 1023) / 1024;   // 147
        block_sum_kernel<<<nscan, 256, 0, stream>>>(row_off, bsum, N_NODES);
        scan_bsum_kernel<<<1, 256, 0, stream>>>(bsum, nscan);
        scan_write_kernel<<<nscan, 256, 0, stream>>>(row_off, bsum, row_ptr, N_NODES, nnz);

        // 3. position scatter -> sorted (col,val)
        hipMemsetAsync(row_off, 0, N_NODES * sizeof(int), stream);
        csr_scatter_kernel<<<eblocks, 256, 0, stream>>>(rows, cols, vals, row_ptr, row_off,
                                                        scol, sval, nnz);

        // 4. init x = out = emb0
        int iblocks = (total4 + 255) / 256;
        init4_kernel<<<iblocks, 256, 0, stream>>>((const float4*)user, (const float4*)item,
                                                  (float4*)bufA, (float4*)out, n_user4, total4);

        // 5. 3 fused gather-SpMM layers
        float* x = bufA; float* y = bufB;
        int sblocks = (N_NODES * 64 + 255) / 256;   // 1 wave per row
        for (int layer = 0; layer < 3; ++layer) {
            float fs = (layer == 2) ? 0.25f : 1.0f;
            spmm_csr_kernel<<<sblocks, 256, 0, stream>>>(row_ptr, scol, sval, x, y, out, fs);
            float* t = x; x = y; y = t;
        }
    } else {
        // fallback: atomic scatter path (round-0)
        int iblocks = (total4 + 255) / 256;
        init4_kernel<<<iblocks, 256, 0, stream>>>((const float4*)user, (const float4*)item,
                                                  (float4*)bufA, (float4*)out, n_user4, total4);
        float* x = bufA; float* y = bufB;
        for (int layer = 0; layer < 3; ++layer) {
            hipMemsetAsync(y, 0, nfloats * sizeof(float), stream);
            unsigned int threads = (unsigned int)nnz * 16u;
            unsigned int blocks = (threads + 255u) / 256u;
            spmm_scatter_kernel<<<blocks, 256, 0, stream>>>(rows, cols, vals,
                                                            (const float4*)x, y, nnz);
            float scale = (layer == 2) ? 0.25f : 1.0f;
            int ablocks = (total4 + 255) / 256;
            acc4_kernel<<<ablocks, 256, 0, stream>>>((float4*)out, (const float4*)y, total4, scale);
            float* t = x; x = y; y = t;
        }
    }
}

// Round 7
// 1692.645 us; speedup vs baseline: 12.0076x; 1.3366x over previous
//
#include <hip/hip_runtime.h>

#define N_USERS 100000
#define N_ITEMS 50000
#define N_NODES 150000
#define EMBED_DIM 64

// ===========================================================================
// init: x = acc = concat(user_embedding, item_embedding)
// ===========================================================================
__global__ void init4_kernel(const float4* __restrict__ user,
                             const float4* __restrict__ item,
                             float4* __restrict__ x,
                             float4* __restrict__ acc,
                             int n_user4, int total4) {
    int i = blockIdx.x * blockDim.x + threadIdx.x;
    if (i < total4) {
        float4 v = (i < n_user4) ? user[i] : item[i - n_user4];
        x[i] = v;
        acc[i] = v;
    }
}

// ===========================================================================
// CSR build: histogram -> exclusive scan -> packed int2 scatter
// ===========================================================================
__global__ void hist_kernel(const int* __restrict__ rows, int* __restrict__ cnt, int nnz) {
    int e = blockIdx.x * blockDim.x + threadIdx.x;
    if (e < nnz) atomicAdd(&cnt[rows[e]], 1);
}

__global__ void block_sum_kernel(const int* __restrict__ cnt, int* __restrict__ bsum, int n) {
    __shared__ int lds[256];
    int tid = threadIdx.x;
    int base = blockIdx.x * 1024 + tid * 4;
    int s = 0;
#pragma unroll
    for (int j = 0; j < 4; ++j) { int idx = base + j; if (idx < n) s += cnt[idx]; }
    lds[tid] = s; __syncthreads();
    for (int off = 128; off > 0; off >>= 1) {
        if (tid < off) lds[tid] += lds[tid + off];
        __syncthreads();
    }
    if (tid == 0) bsum[blockIdx.x] = lds[0];
}

__global__ void scan_bsum_kernel(int* __restrict__ bsum, int nb) {
    __shared__ int lds[256];
    int tid = threadIdx.x;
    int v = (tid < nb) ? bsum[tid] : 0;
    lds[tid] = v; __syncthreads();
    for (int off = 1; off < 256; off <<= 1) {
        int t = (tid >= off) ? lds[tid - off] : 0;
        __syncthreads();
        lds[tid] += t;
        __syncthreads();
    }
    if (tid < nb) bsum[tid] = lds[tid] - v;   // exclusive
}

__global__ void scan_write_kernel(const int* __restrict__ cnt, const int* __restrict__ bsum,
                                  int* __restrict__ row_ptr, int n, int nnz) {
    __shared__ int lds[256];
    int tid = threadIdx.x;
    int base = blockIdx.x * 1024 + tid * 4;
    int v[4]; int s = 0;
#pragma unroll
    for (int j = 0; j < 4; ++j) { int idx = base + j; v[j] = (idx < n) ? cnt[idx] : 0; s += v[j]; }
    lds[tid] = s; __syncthreads();
    for (int off = 1; off < 256; off <<= 1) {
        int t = (tid >= off) ? lds[tid - off] : 0;
        __syncthreads();
        lds[tid] += t;
        __syncthreads();
    }
    int run = lds[tid] - s + bsum[blockIdx.x];
#pragma unroll
    for (int j = 0; j < 4; ++j) {
        int idx = base + j;
        if (idx < n) row_ptr[idx] = run;
        run += v[j];
    }
    if (blockIdx.x == 0 && tid == 0) row_ptr[n] = nnz;
}

// packed (col, val-bits) scatter: one 8B store per edge
__global__ void csr_scatter_kernel(const int* __restrict__ rows, const int* __restrict__ cols,
                                   const float* __restrict__ vals,
                                   const int* __restrict__ row_ptr, int* __restrict__ row_off,
                                   int2* __restrict__ edges, int nnz) {
    int e = blockIdx.x * blockDim.x + threadIdx.x;
    if (e >= nnz) return;
    int r = rows[e];
    int idx = row_ptr[r] + atomicAdd(&row_off[r], 1);
    edges[idx] = make_int2(cols[e], __float_as_int(vals[e]));
}

// ===========================================================================
// Row-parallel gather SpMM, 4 edges / iteration:
//   wave = row; 4 lane-groups of 16; group g handles edge j*4+g;
//   lane gl in group loads float4 chunk gl of x[col]; cross-group
//   __shfl_xor reduction at the end; y written once; acc fused.
// ===========================================================================
__global__ __launch_bounds__(256) void spmm_csr_kernel(
        const int* __restrict__ row_ptr, const int2* __restrict__ edges,
        const float4* __restrict__ x4,
        float4* __restrict__ y4, float4* __restrict__ out4, float final_scale) {
    int wid = (blockIdx.x * blockDim.x + threadIdx.x) >> 6;   // wave id = row
    int lane = threadIdx.x & 63;
    if (wid >= N_NODES) return;

    int start = row_ptr[wid];
    int end = row_ptr[wid + 1];
    int g  = lane >> 4;     // group 0..3
    int gl = lane & 15;     // lane within group = float4 chunk of the 64-dim row

    float4 acc = make_float4(0.f, 0.f, 0.f, 0.f);

    for (int base = start; base < end; base += 64) {
        int e = base + lane;
        int c = 0; float v = 0.0f;
        if (e < end) {
            int2 ev = edges[e];
            c = ev.x; v = __int_as_float(ev.y);
        }
        int nj = end - base; if (nj > 64) nj = 64;
        int jmax = (nj + 3) >> 2;   // 4 edges per iteration
#pragma unroll 4
        for (int j = 0; j < jmax; ++j) {
            int src = j * 4 + g;              // lane holding this group's edge
            int   cj = __shfl(c, src, 64);    // v==0 for padded lanes
            float vj = __shfl(v, src, 64);
            float4 xv = x4[(size_t)cj * 16 + gl];
            acc.x += vj * xv.x;
            acc.y += vj * xv.y;
            acc.z += vj * xv.z;
            acc.w += vj * xv.w;
        }
    }

    // reduce across the 4 groups (lanes gl, gl+16, gl+32, gl+48)
#pragma unroll
    for (int off = 16; off < 64; off <<= 1) {
        acc.x += __shfl_xor(acc.x, off, 64);
        acc.y += __shfl_xor(acc.y, off, 64);
        acc.z += __shfl_xor(acc.z, off, 64);
        acc.w += __shfl_xor(acc.w, off, 64);
    }

    if (lane < 16) {
        size_t o = (size_t)wid * 16 + gl;
        y4[o] = acc;
        float4 ov = out4[o];
        ov.x = (ov.x + acc.x) * final_scale;
        ov.y = (ov.y + acc.y) * final_scale;
        ov.z = (ov.z + acc.z) * final_scale;
        ov.w = (ov.w + acc.w) * final_scale;
        out4[o] = ov;
    }
}

// ===========================================================================
extern "C" void kernel_launch(void* const* d_in, const int* in_sizes, int n_in,
                              void* d_out, int out_size, void* d_ws, size_t ws_size,
                              hipStream_t stream) {
    const float* user = (const float*)d_in[0];
    const float* item = (const float*)d_in[1];
    const int*   rows = (const int*)d_in[2];
    const int*   cols = (const int*)d_in[3];
    const float* vals = (const float*)d_in[4];
    float* out = (float*)d_out;

    const int nnz = in_sizes[2];
    const size_t nfloats = (size_t)N_NODES * EMBED_DIM;   // 9.6M
    const int total4 = (int)(nfloats / 4);
    const int n_user4 = (N_USERS * EMBED_DIM) / 4;

    // ---- workspace layout (256B-aligned regions) ----
    char* ws = (char*)d_ws;
    size_t off = 0;
    auto alloc = [&](size_t bytes) { size_t p = off; off += (bytes + 255) & ~(size_t)255; return p; };
    size_t o_bufA  = alloc(nfloats * sizeof(float));
    size_t o_bufB  = alloc(nfloats * sizeof(float));
    size_t o_rptr  = alloc((N_NODES + 1) * sizeof(int));
    size_t o_roff  = alloc(N_NODES * sizeof(int));
    size_t o_bsum  = alloc(256 * sizeof(int));
    size_t o_edges = alloc((size_t)nnz * sizeof(int2));

    float* bufA = (float*)(ws + o_bufA);
    float* bufB = (float*)(ws + o_bufB);
    int* row_ptr = (int*)(ws + o_rptr);
    int* row_off = (int*)(ws + o_roff);
    int* bsum    = (int*)(ws + o_bsum);
    int2* edges  = (int2*)(ws + o_edges);

    // 1. histogram
    hipMemsetAsync(row_off, 0, N_NODES * sizeof(int), stream);
    int eblocks = (nnz + 255) / 256;
    hist_kernel<<<eblocks, 256, 0, stream>>>(rows, row_off, nnz);

    // 2. exclusive scan -> row_ptr
    int nscan = (N_NODES + 1023) / 1024;   // 147
    block_sum_kernel<<<nscan, 256, 0, stream>>>(row_off, bsum, N_NODES);
    scan_bsum_kernel<<<1, 256, 0, stream>>>(bsum, nscan);
    scan_write_kernel<<<nscan, 256, 0, stream>>>(row_off, bsum, row_ptr, N_NODES, nnz);

    // 3. packed position scatter -> edges[]
    hipMemsetAsync(row_off, 0, N_NODES * sizeof(int), stream);
    csr_scatter_kernel<<<eblocks, 256, 0, stream>>>(rows, cols, vals, row_ptr, row_off,
                                                    edges, nnz);

    // 4. init x = out = emb0
    int iblocks = (total4 + 255) / 256;
    init4_kernel<<<iblocks, 256, 0, stream>>>((const float4*)user, (const float4*)item,
                                              (float4*)bufA, (float4*)out, n_user4, total4);

    // 5. 3 fused gather-SpMM layers
    float* x = bufA; float* y = bufB;
    int sblocks = (N_NODES * 64 + 255) / 256;   // 1 wave per row
    for (int layer = 0; layer < 3; ++layer) {
        float fs = (layer == 2) ? 0.25f : 1.0f;
        spmm_csr_kernel<<<sblocks, 256, 0, stream>>>(row_ptr, edges,
                                                     (const float4*)x,
                                                     (float4*)y, (float4*)out, fs);
        float* t = x; x = y; y = t;
    }
}

// Round 8
// 1563.250 us; speedup vs baseline: 13.0015x; 1.0828x over previous
//
#include <hip/hip_runtime.h>

#define N_USERS 100000
#define N_ITEMS 50000
#define N_NODES 150000
#define EMBED_DIM 64

// ===========================================================================
// init: x = acc = concat(user_embedding, item_embedding)
// ===========================================================================
__global__ void init4_kernel(const float4* __restrict__ user,
                             const float4* __restrict__ item,
                             float4* __restrict__ x,
                             float4* __restrict__ acc,
                             int n_user4, int total4) {
    int i = blockIdx.x * blockDim.x + threadIdx.x;
    if (i < total4) {
        float4 v = (i < n_user4) ? user[i] : item[i - n_user4];
        x[i] = v;
        acc[i] = v;
    }
}

// ===========================================================================
// CSR build: hist+rank -> exclusive scan -> rank-directed scatter (no atomics)
// ===========================================================================
__global__ void hist_rank_kernel(const int* __restrict__ rows, int* __restrict__ cnt,
                                 int* __restrict__ rank, int nnz) {
    int e = blockIdx.x * blockDim.x + threadIdx.x;
    if (e < nnz) rank[e] = atomicAdd(&cnt[rows[e]], 1);
}

__global__ void block_sum_kernel(const int* __restrict__ cnt, int* __restrict__ bsum, int n) {
    __shared__ int lds[256];
    int tid = threadIdx.x;
    int base = blockIdx.x * 1024 + tid * 4;
    int s = 0;
#pragma unroll
    for (int j = 0; j < 4; ++j) { int idx = base + j; if (idx < n) s += cnt[idx]; }
    lds[tid] = s; __syncthreads();
    for (int off = 128; off > 0; off >>= 1) {
        if (tid < off) lds[tid] += lds[tid + off];
        __syncthreads();
    }
    if (tid == 0) bsum[blockIdx.x] = lds[0];
}

__global__ void scan_bsum_kernel(int* __restrict__ bsum, int nb) {
    __shared__ int lds[256];
    int tid = threadIdx.x;
    int v = (tid < nb) ? bsum[tid] : 0;
    lds[tid] = v; __syncthreads();
    for (int off = 1; off < 256; off <<= 1) {
        int t = (tid >= off) ? lds[tid - off] : 0;
        __syncthreads();
        lds[tid] += t;
        __syncthreads();
    }
    if (tid < nb) bsum[tid] = lds[tid] - v;   // exclusive
}

__global__ void scan_write_kernel(const int* __restrict__ cnt, const int* __restrict__ bsum,
                                  int* __restrict__ row_ptr, int n, int nnz) {
    __shared__ int lds[256];
    int tid = threadIdx.x;
    int base = blockIdx.x * 1024 + tid * 4;
    int v[4]; int s = 0;
#pragma unroll
    for (int j = 0; j < 4; ++j) { int idx = base + j; v[j] = (idx < n) ? cnt[idx] : 0; s += v[j]; }
    lds[tid] = s; __syncthreads();
    for (int off = 1; off < 256; off <<= 1) {
        int t = (tid >= off) ? lds[tid - off] : 0;
        __syncthreads();
        lds[tid] += t;
        __syncthreads();
    }
    int run = lds[tid] - s + bsum[blockIdx.x];
#pragma unroll
    for (int j = 0; j < 4; ++j) {
        int idx = base + j;
        if (idx < n) row_ptr[idx] = run;
        run += v[j];
    }
    if (blockIdx.x == 0 && tid == 0) row_ptr[n] = nnz;
}

// rank-directed scatter: pure load->store, no atomics
__global__ void csr_scatter_kernel(const int* __restrict__ rows, const int* __restrict__ cols,
                                   const float* __restrict__ vals,
                                   const int* __restrict__ row_ptr, const int* __restrict__ rank,
                                   int2* __restrict__ edges, int nnz) {
    int e = blockIdx.x * blockDim.x + threadIdx.x;
    if (e >= nnz) return;
    int idx = row_ptr[rows[e]] + rank[e];
    edges[idx] = make_int2(cols[e], __float_as_int(vals[e]));
}

// ===========================================================================
// Row-parallel gather SpMM, 4 edges / iteration, direct broadcast edge loads:
//   wave = row; 4 lane-groups of 16; group g loads edge j*4+g directly
//   (32B contiguous per wave-instr, L1 broadcast within group); lane gl
//   loads float4 chunk gl of x[col]; cross-group shfl_xor reduce at end.
// ===========================================================================
__global__ __launch_bounds__(256) void spmm_csr_kernel(
        const int* __restrict__ row_ptr, const int2* __restrict__ edges,
        const float4* __restrict__ x4,
        float4* __restrict__ y4, float4* __restrict__ out4,
        float final_scale, int write_y) {
    int wid = (blockIdx.x * blockDim.x + threadIdx.x) >> 6;   // wave id = row
    int lane = threadIdx.x & 63;
    if (wid >= N_NODES) return;

    int start = row_ptr[wid];
    int nj = row_ptr[wid + 1] - start;
    int g  = lane >> 4;     // group 0..3
    int gl = lane & 15;     // float4 chunk of the 64-dim row

    const int2* ep = edges + start;
    float4 acc = make_float4(0.f, 0.f, 0.f, 0.f);

    int jmax = (nj + 3) >> 2;
#pragma unroll 4
    for (int j = 0; j < jmax; ++j) {
        int idx = (j << 2) + g;
        bool ok = idx < nj;
        int2 ev = ep[ok ? idx : 0];            // clamp keeps address valid
        float v = ok ? __int_as_float(ev.y) : 0.0f;
        float4 xv = x4[ev.x * 16 + gl];
        acc.x += v * xv.x;
        acc.y += v * xv.y;
        acc.z += v * xv.z;
        acc.w += v * xv.w;
    }

    // reduce across the 4 groups (lanes gl, gl+16, gl+32, gl+48)
#pragma unroll
    for (int off = 16; off < 64; off <<= 1) {
        acc.x += __shfl_xor(acc.x, off, 64);
        acc.y += __shfl_xor(acc.y, off, 64);
        acc.z += __shfl_xor(acc.z, off, 64);
        acc.w += __shfl_xor(acc.w, off, 64);
    }

    if (lane < 16) {
        int o = wid * 16 + gl;
        if (write_y) y4[o] = acc;
        float4 ov = out4[o];
        ov.x = (ov.x + acc.x) * final_scale;
        ov.y = (ov.y + acc.y) * final_scale;
        ov.z = (ov.z + acc.z) * final_scale;
        ov.w = (ov.w + acc.w) * final_scale;
        out4[o] = ov;
    }
}

// ===========================================================================
extern "C" void kernel_launch(void* const* d_in, const int* in_sizes, int n_in,
                              void* d_out, int out_size, void* d_ws, size_t ws_size,
                              hipStream_t stream) {
    const float* user = (const float*)d_in[0];
    const float* item = (const float*)d_in[1];
    const int*   rows = (const int*)d_in[2];
    const int*   cols = (const int*)d_in[3];
    const float* vals = (const float*)d_in[4];
    float* out = (float*)d_out;

    const int nnz = in_sizes[2];
    const size_t nfloats = (size_t)N_NODES * EMBED_DIM;   // 9.6M
    const int total4 = (int)(nfloats / 4);
    const int n_user4 = (N_USERS * EMBED_DIM) / 4;

    // ---- workspace layout (256B-aligned regions) ----
    char* ws = (char*)d_ws;
    size_t off = 0;
    auto alloc = [&](size_t bytes) { size_t p = off; off += (bytes + 255) & ~(size_t)255; return p; };
    size_t o_bufA  = alloc(nfloats * sizeof(float));
    size_t o_bufB  = alloc(nfloats * sizeof(float));   // also overlays rank[] pre-SpMM
    size_t o_rptr  = alloc((N_NODES + 1) * sizeof(int));
    size_t o_roff  = alloc(N_NODES * sizeof(int));
    size_t o_bsum  = alloc(256 * sizeof(int));
    size_t o_edges = alloc(((size_t)nnz + 8) * sizeof(int2));

    float* bufA = (float*)(ws + o_bufA);
    float* bufB = (float*)(ws + o_bufB);
    int* row_ptr = (int*)(ws + o_rptr);
    int* cnt     = (int*)(ws + o_roff);
    int* bsum    = (int*)(ws + o_bsum);
    int* rank    = (int*)(ws + o_bufB);    // overlay: dead until SpMM layer 1 writes y
    int2* edges  = (int2*)(ws + o_edges);
    (void)ws_size;

    // 1. histogram + per-edge rank
    hipMemsetAsync(cnt, 0, N_NODES * sizeof(int), stream);
    int eblocks = (nnz + 255) / 256;
    hist_rank_kernel<<<eblocks, 256, 0, stream>>>(rows, cnt, rank, nnz);

    // 2. exclusive scan -> row_ptr
    int nscan = (N_NODES + 1023) / 1024;   // 147
    block_sum_kernel<<<nscan, 256, 0, stream>>>(cnt, bsum, N_NODES);
    scan_bsum_kernel<<<1, 256, 0, stream>>>(bsum, nscan);
    scan_write_kernel<<<nscan, 256, 0, stream>>>(cnt, bsum, row_ptr, N_NODES, nnz);

    // 3. rank-directed scatter (no atomics)
    csr_scatter_kernel<<<eblocks, 256, 0, stream>>>(rows, cols, vals, row_ptr, rank,
                                                    edges, nnz);

    // 4. init x = out = emb0
    int iblocks = (total4 + 255) / 256;
    init4_kernel<<<iblocks, 256, 0, stream>>>((const float4*)user, (const float4*)item,
                                              (float4*)bufA, (float4*)out, n_user4, total4);

    // 5. 3 fused gather-SpMM layers
    float* x = bufA; float* y = bufB;
    int sblocks = (N_NODES * 64 + 255) / 256;   // 1 wave per row
    for (int layer = 0; layer < 3; ++layer) {
        float fs = (layer == 2) ? 0.25f : 1.0f;
        int wy = (layer == 2) ? 0 : 1;
        spmm_csr_kernel<<<sblocks, 256, 0, stream>>>(row_ptr, edges,
                                                     (const float4*)x,
                                                     (float4*)y, (float4*)out, fs, wy);
        float* t = x; x = y; y = t;
    }
}

// Round 11
// 1528.866 us; speedup vs baseline: 13.2939x; 1.0225x over previous
//
#include <hip/hip_runtime.h>

#define N_USERS 100000
#define N_ITEMS 50000
#define N_NODES 150000
#define EMBED_DIM 64
#define CNT_STRIDE 8   // one 32B sector per histogram bin

// ===========================================================================
// init: x = acc = concat(user_embedding, item_embedding)
// ===========================================================================
__global__ void init4_kernel(const float4* __restrict__ user,
                             const float4* __restrict__ item,
                             float4* __restrict__ x,
                             float4* __restrict__ acc,
                             int n_user4, int total4) {
    int i = blockIdx.x * blockDim.x + threadIdx.x;
    if (i < total4) {
        float4 v = (i < n_user4) ? user[i] : item[i - n_user4];
        x[i] = v;
        acc[i] = v;
    }
}

// ===========================================================================
// CSR build: hist+rank (padded bins) -> exclusive scan -> rank-directed scatter
// ===========================================================================
__global__ void hist_rank_kernel(const int* __restrict__ rows, int* __restrict__ cnt,
                                 int* __restrict__ rank, int nnz) {
    int e = blockIdx.x * blockDim.x + threadIdx.x;
    if (e < nnz) rank[e] = atomicAdd(&cnt[rows[e] * CNT_STRIDE], 1);
}

__global__ void block_sum_kernel(const int* __restrict__ cnt, int* __restrict__ bsum, int n) {
    __shared__ int lds[256];
    int tid = threadIdx.x;
    int base = blockIdx.x * 1024 + tid * 4;
    int s = 0;
#pragma unroll
    for (int j = 0; j < 4; ++j) { int idx = base + j; if (idx < n) s += cnt[idx * CNT_STRIDE]; }
    lds[tid] = s; __syncthreads();
    for (int off = 128; off > 0; off >>= 1) {
        if (tid < off) lds[tid] += lds[tid + off];
        __syncthreads();
    }
    if (tid == 0) bsum[blockIdx.x] = lds[0];
}

__global__ void scan_bsum_kernel(int* __restrict__ bsum, int nb) {
    __shared__ int lds[256];
    int tid = threadIdx.x;
    int v = (tid < nb) ? bsum[tid] : 0;
    lds[tid] = v; __syncthreads();
    for (int off = 1; off < 256; off <<= 1) {
        int t = (tid >= off) ? lds[tid - off] : 0;
        __syncthreads();
        lds[tid] += t;
        __syncthreads();
    }
    if (tid < nb) bsum[tid] = lds[tid] - v;   // exclusive
}

__global__ void scan_write_kernel(const int* __restrict__ cnt, const int* __restrict__ bsum,
                                  int* __restrict__ row_ptr, int n, int nnz) {
    __shared__ int lds[256];
    int tid = threadIdx.x;
    int base = blockIdx.x * 1024 + tid * 4;
    int v[4]; int s = 0;
#pragma unroll
    for (int j = 0; j < 4; ++j) { int idx = base + j; v[j] = (idx < n) ? cnt[idx * CNT_STRIDE] : 0; s += v[j]; }
    lds[tid] = s; __syncthreads();
    for (int off = 1; off < 256; off <<= 1) {
        int t = (tid >= off) ? lds[tid - off] : 0;
        __syncthreads();
        lds[tid] += t;
        __syncthreads();
    }
    int run = lds[tid] - s + bsum[blockIdx.x];
#pragma unroll
    for (int j = 0; j < 4; ++j) {
        int idx = base + j;
        if (idx < n) row_ptr[idx] = run;
        run += v[j];
    }
    if (blockIdx.x == 0 && tid == 0) row_ptr[n] = nnz;
}

// rank-directed scatter: pure load->store, no atomics
__global__ void csr_scatter_kernel(const int* __restrict__ rows, const int* __restrict__ cols,
                                   const float* __restrict__ vals,
                                   const int* __restrict__ row_ptr, const int* __restrict__ rank,
                                   int2* __restrict__ edges, int nnz) {
    int e = blockIdx.x * blockDim.x + threadIdx.x;
    if (e >= nnz) return;
    int idx = row_ptr[rows[e]] + rank[e];
    edges[idx] = make_int2(cols[e], __float_as_int(vals[e]));
}

// ===========================================================================
// Row-parallel gather SpMM, 8 edges / iteration, two accumulator chains:
//   wave = row; 4 lane-groups of 16; group g handles edges j*8+g and j*8+4+g;
//   lane gl loads float4 chunk gl of x[col]; cross-group shfl_xor reduce.
// ===========================================================================
__global__ __launch_bounds__(256) void spmm_csr_kernel(
        const int* __restrict__ row_ptr, const int2* __restrict__ edges,
        const float4* __restrict__ x4,
        float4* __restrict__ y4, float4* __restrict__ out4,
        float final_scale, int write_y) {
    int wid = (blockIdx.x * blockDim.x + threadIdx.x) >> 6;   // wave id = row
    int lane = threadIdx.x & 63;
    if (wid >= N_NODES) return;

    int start = row_ptr[wid];
    int nj = row_ptr[wid + 1] - start;
    int g  = lane >> 4;     // group 0..3
    int gl = lane & 15;     // float4 chunk of the 64-dim row

    const int2* ep = edges + start;
    float4 acc0 = make_float4(0.f, 0.f, 0.f, 0.f);
    float4 acc1 = make_float4(0.f, 0.f, 0.f, 0.f);

    int jmax = (nj + 7) >> 3;   // 8 edges per iteration
    for (int j = 0; j < jmax; ++j) {
        int i0 = (j << 3) + g;
        int i1 = i0 + 4;
        bool ok0 = i0 < nj;
        bool ok1 = i1 < nj;
        int2 ev0 = ep[ok0 ? i0 : 0];
        int2 ev1 = ep[ok1 ? i1 : 0];
        float v0 = ok0 ? __int_as_float(ev0.y) : 0.0f;
        float v1 = ok1 ? __int_as_float(ev1.y) : 0.0f;
        float4 xv0 = x4[ev0.x * 16 + gl];
        float4 xv1 = x4[ev1.x * 16 + gl];
        acc0.x += v0 * xv0.x;  acc0.y += v0 * xv0.y;
        acc0.z += v0 * xv0.z;  acc0.w += v0 * xv0.w;
        acc1.x += v1 * xv1.x;  acc1.y += v1 * xv1.y;
        acc1.z += v1 * xv1.z;  acc1.w += v1 * xv1.w;
    }

    float4 acc;
    acc.x = acc0.x + acc1.x;
    acc.y = acc0.y + acc1.y;
    acc.z = acc0.z + acc1.z;
    acc.w = acc0.w + acc1.w;

    // reduce across the 4 groups (lanes gl, gl+16, gl+32, gl+48)
#pragma unroll
    for (int off = 16; off < 64; off <<= 1) {
        acc.x += __shfl_xor(acc.x, off, 64);
        acc.y += __shfl_xor(acc.y, off, 64);
        acc.z += __shfl_xor(acc.z, off, 64);
        acc.w += __shfl_xor(acc.w, off, 64);
    }

    if (lane < 16) {
        int o = wid * 16 + gl;
        if (write_y) y4[o] = acc;
        float4 ov = out4[o];
        ov.x = (ov.x + acc.x) * final_scale;
        ov.y = (ov.y + acc.y) * final_scale;
        ov.z = (ov.z + acc.z) * final_scale;
        ov.w = (ov.w + acc.w) * final_scale;
        out4[o] = ov;
    }
}

// ===========================================================================
extern "C" void kernel_launch(void* const* d_in, const int* in_sizes, int n_in,
                              void* d_out, int out_size, void* d_ws, size_t ws_size,
                              hipStream_t stream) {
    const float* user = (const float*)d_in[0];
    const float* item = (const float*)d_in[1];
    const int*   rows = (const int*)d_in[2];
    const int*   cols = (const int*)d_in[3];
    const float* vals = (const float*)d_in[4];
    float* out = (float*)d_out;

    const int nnz = in_sizes[2];
    const size_t nfloats = (size_t)N_NODES * EMBED_DIM;   // 9.6M
    const int total4 = (int)(nfloats / 4);
    const int n_user4 = (N_USERS * EMBED_DIM) / 4;

    // ---- workspace layout (256B-aligned regions) ----
    char* ws = (char*)d_ws;
    size_t off = 0;
    auto alloc = [&](size_t bytes) { size_t p = off; off += (bytes + 255) & ~(size_t)255; return p; };
    size_t o_bufA  = alloc(nfloats * sizeof(float));
    size_t o_bufB  = alloc(nfloats * sizeof(float));   // also overlays rank[] pre-SpMM
    size_t o_rptr  = alloc((N_NODES + 1) * sizeof(int));
    size_t o_cnt   = alloc((size_t)N_NODES * CNT_STRIDE * sizeof(int));  // 4.8 MB padded bins
    size_t o_bsum  = alloc(256 * sizeof(int));
    size_t o_edges = alloc(((size_t)nnz + 8) * sizeof(int2));

    float* bufA = (float*)(ws + o_bufA);
    float* bufB = (float*)(ws + o_bufB);
    int* row_ptr = (int*)(ws + o_rptr);
    int* cnt     = (int*)(ws + o_cnt);
    int* bsum    = (int*)(ws + o_bsum);
    int* rank    = (int*)(ws + o_bufB);    // overlay: dead until SpMM layer 0 writes y
    int2* edges  = (int2*)(ws + o_edges);
    (void)ws_size;

    // 1. histogram + per-edge rank (padded bins: 1 bin per 32B sector)
    hipMemsetAsync(cnt, 0, (size_t)N_NODES * CNT_STRIDE * sizeof(int), stream);
    int eblocks = (nnz + 255) / 256;
    hist_rank_kernel<<<eblocks, 256, 0, stream>>>(rows, cnt, rank, nnz);

    // 2. exclusive scan -> row_ptr
    int nscan = (N_NODES + 1023) / 1024;   // 147
    block_sum_kernel<<<nscan, 256, 0, stream>>>(cnt, bsum, N_NODES);
    scan_bsum_kernel<<<1, 256, 0, stream>>>(bsum, nscan);
    scan_write_kernel<<<nscan, 256, 0, stream>>>(cnt, bsum, row_ptr, N_NODES, nnz);

    // 3. rank-directed scatter (no atomics)
    csr_scatter_kernel<<<eblocks, 256, 0, stream>>>(rows, cols, vals, row_ptr, rank,
                                                    edges, nnz);

    // 4. init x = out = emb0
    int iblocks = (total4 + 255) / 256;
    init4_kernel<<<iblocks, 256, 0, stream>>>((const float4*)user, (const float4*)item,
                                              (float4*)bufA, (float4*)out, n_user4, total4);

    // 5. 3 fused gather-SpMM layers
    float* x = bufA; float* y = bufB;
    int sblocks = (N_NODES * 64 + 255) / 256;   // 1 wave per row
    for (int layer = 0; layer < 3; ++layer) {
        float fs = (layer == 2) ? 0.25f : 1.0f;
        int wy = (layer == 2) ? 0 : 1;
        spmm_csr_kernel<<<sblocks, 256, 0, stream>>>(row_ptr, edges,
                                                     (const float4*)x,
                                                     (float4*)y, (float4*)out, fs, wy);
        float* t = x; x = y; y = t;
    }
}

// Round 12
// 1243.085 us; speedup vs baseline: 16.3501x; 1.2299x over previous
//
#include <hip/hip_runtime.h>

#define N_USERS 100000
#define N_ITEMS 50000
#define N_NODES 150000
#define EMBED_DIM 64

#define BUCKET_SHIFT 7                 // 128 rows per bucket
#define NB 1172                        // ceil(150000 / 128)
#define NBLK 512                       // partition blocks (scanA assumes == 2*256)

// ===========================================================================
// init: x = acc = concat(user_embedding, item_embedding)
// ===========================================================================
__global__ void init4_kernel(const float4* __restrict__ user,
                             const float4* __restrict__ item,
                             float4* __restrict__ x,
                             float4* __restrict__ acc,
                             int n_user4, int total4) {
    int i = blockIdx.x * blockDim.x + threadIdx.x;
    if (i < total4) {
        float4 v = (i < n_user4) ? user[i] : item[i - n_user4];
        x[i] = v;
        acc[i] = v;
    }
}

// ===========================================================================
// P0: per-block LDS histogram over row-buckets (no global atomics)
// blk_cnt layout: [block][bucket]
// ===========================================================================
__global__ __launch_bounds__(256) void part_count_kernel(const int* __restrict__ rows,
                                                         int* __restrict__ blk_cnt, int nnz) {
    __shared__ int cnt[NB];
    for (int i = threadIdx.x; i < NB; i += 256) cnt[i] = 0;
    __syncthreads();
    int b = blockIdx.x;
    int chunk = (nnz + NBLK - 1) / NBLK;
    int s = b * chunk, e = min(nnz, s + chunk);
    for (int i = s + threadIdx.x; i < e; i += 256)
        atomicAdd(&cnt[rows[i] >> BUCKET_SHIFT], 1);
    __syncthreads();
    for (int i = threadIdx.x; i < NB; i += 256) blk_cnt[b * NB + i] = cnt[i];
}

// ===========================================================================
// scanA: per bucket, exclusive scan over the NBLK per-block counts (in place);
// bucket total -> bkt_tot. One block per bucket; thread t handles b=2t, 2t+1.
// ===========================================================================
__global__ __launch_bounds__(256) void scan_blocks_kernel(int* __restrict__ blk_cnt,
                                                          int* __restrict__ bkt_tot) {
    __shared__ int lds[256];
    int nb = blockIdx.x, tid = threadIdx.x;
    int v0 = blk_cnt[(2 * tid) * NB + nb];
    int v1 = blk_cnt[(2 * tid + 1) * NB + nb];
    int s = v0 + v1;
    lds[tid] = s; __syncthreads();
    for (int off = 1; off < 256; off <<= 1) {
        int t = (tid >= off) ? lds[tid - off] : 0;
        __syncthreads();
        lds[tid] += t;
        __syncthreads();
    }
    int excl = lds[tid] - s;
    blk_cnt[(2 * tid) * NB + nb] = excl;
    blk_cnt[(2 * tid + 1) * NB + nb] = excl + v0;
    if (tid == 255) bkt_tot[nb] = lds[255];
}

// ===========================================================================
// scanB: exclusive scan over NB bucket totals -> bucket_start[NB+1]
// single block, 5 values per thread (NB <= 1280)
// ===========================================================================
__global__ __launch_bounds__(256) void scan_buckets_kernel(const int* __restrict__ bkt_tot,
                                                           int* __restrict__ bucket_start, int nnz) {
    __shared__ int lds[256];
    int tid = threadIdx.x;
    int v[5]; int s = 0;
#pragma unroll
    for (int j = 0; j < 5; ++j) {
        int idx = tid * 5 + j;
        v[j] = (idx < NB) ? bkt_tot[idx] : 0;
        s += v[j];
    }
    lds[tid] = s; __syncthreads();
    for (int off = 1; off < 256; off <<= 1) {
        int t = (tid >= off) ? lds[tid - off] : 0;
        __syncthreads();
        lds[tid] += t;
        __syncthreads();
    }
    int run = lds[tid] - s;
#pragma unroll
    for (int j = 0; j < 5; ++j) {
        int idx = tid * 5 + j;
        if (idx < NB) bucket_start[idx] = run;
        run += v[j];
    }
    if (tid == 0) bucket_start[NB] = nnz;
}

// ===========================================================================
// P1: partition edges into bucket-ordered array via LDS cursors.
// Each block owns a private contiguous range per bucket (no global atomics).
// part entry: (local_row<<18 | col, val_bits)
// ===========================================================================
__global__ __launch_bounds__(256) void partition_kernel(const int* __restrict__ rows,
                                                        const int* __restrict__ cols,
                                                        const float* __restrict__ vals,
                                                        const int* __restrict__ blk_cnt,
                                                        const int* __restrict__ bucket_start,
                                                        int2* __restrict__ part, int nnz) {
    __shared__ int cur[NB];
    int b = blockIdx.x;
    for (int i = threadIdx.x; i < NB; i += 256)
        cur[i] = bucket_start[i] + blk_cnt[b * NB + i];
    __syncthreads();
    int chunk = (nnz + NBLK - 1) / NBLK;
    int s = b * chunk, e = min(nnz, s + chunk);
    for (int i = s + threadIdx.x; i < e; i += 256) {
        int r = rows[i];
        int nb = r >> BUCKET_SHIFT;
        int rl = r & 127;
        int pos = atomicAdd(&cur[nb], 1);
        part[pos] = make_int2((rl << 18) | cols[i], __float_as_int(vals[i]));
    }
}

// ===========================================================================
// P2: per-bucket fine counting sort (128 rows, all in LDS) -> final CSR edges
// + row_ptr emitted directly.
// ===========================================================================
__global__ __launch_bounds__(256) void bucket_sort_kernel(const int2* __restrict__ part,
                                                          const int* __restrict__ bucket_start,
                                                          int* __restrict__ row_ptr,
                                                          int2* __restrict__ edges, int nnz) {
    __shared__ int cnt[128];
    __shared__ int off[128];
    int nb = blockIdx.x, tid = threadIdx.x;
    int base = bucket_start[nb];
    int cntE = bucket_start[nb + 1] - base;

    if (tid < 128) cnt[tid] = 0;
    __syncthreads();
    for (int i = tid; i < cntE; i += 256)
        atomicAdd(&cnt[part[base + i].x >> 18], 1);
    __syncthreads();

    // inclusive scan of cnt into off (tid<128), then convert to exclusive
    if (tid < 128) off[tid] = cnt[tid];
    __syncthreads();
    for (int o = 1; o < 128; o <<= 1) {
        int t = 0;
        if (tid < 128 && tid >= o) t = off[tid - o];
        __syncthreads();
        if (tid < 128) off[tid] += t;
        __syncthreads();
    }
    int r0 = nb << BUCKET_SHIFT;
    if (tid < 128) {
        int excl = off[tid] - cnt[tid];
        off[tid] = excl;                       // now exclusive offsets / cursors
        int r = r0 + tid;
        if (r < N_NODES) row_ptr[r] = base + excl;
    }
    __syncthreads();

    for (int i = tid; i < cntE; i += 256) {
        int2 ev = part[base + i];
        int rl = ev.x >> 18;
        int rank = atomicAdd(&off[rl], 1);
        edges[base + rank] = make_int2(ev.x & 0x3FFFF, ev.y);
    }
    if (nb == 0 && tid == 0) row_ptr[N_NODES] = nnz;
}

// ===========================================================================
// Row-parallel gather SpMM, 8 edges / iteration, two accumulator chains:
//   wave = row; 4 lane-groups of 16; group g handles edges j*8+g and j*8+4+g;
//   lane gl loads float4 chunk gl of x[col]; cross-group shfl_xor reduce.
// ===========================================================================
__global__ __launch_bounds__(256) void spmm_csr_kernel(
        const int* __restrict__ row_ptr, const int2* __restrict__ edges,
        const float4* __restrict__ x4,
        float4* __restrict__ y4, float4* __restrict__ out4,
        float final_scale, int write_y) {
    int wid = (blockIdx.x * blockDim.x + threadIdx.x) >> 6;   // wave id = row
    int lane = threadIdx.x & 63;
    if (wid >= N_NODES) return;

    int start = row_ptr[wid];
    int nj = row_ptr[wid + 1] - start;
    int g  = lane >> 4;     // group 0..3
    int gl = lane & 15;     // float4 chunk of the 64-dim row

    const int2* ep = edges + start;
    float4 acc0 = make_float4(0.f, 0.f, 0.f, 0.f);
    float4 acc1 = make_float4(0.f, 0.f, 0.f, 0.f);

    int jmax = (nj + 7) >> 3;   // 8 edges per iteration
    for (int j = 0; j < jmax; ++j) {
        int i0 = (j << 3) + g;
        int i1 = i0 + 4;
        bool ok0 = i0 < nj;
        bool ok1 = i1 < nj;
        int2 ev0 = ep[ok0 ? i0 : 0];
        int2 ev1 = ep[ok1 ? i1 : 0];
        float v0 = ok0 ? __int_as_float(ev0.y) : 0.0f;
        float v1 = ok1 ? __int_as_float(ev1.y) : 0.0f;
        float4 xv0 = x4[ev0.x * 16 + gl];
        float4 xv1 = x4[ev1.x * 16 + gl];
        acc0.x += v0 * xv0.x;  acc0.y += v0 * xv0.y;
        acc0.z += v0 * xv0.z;  acc0.w += v0 * xv0.w;
        acc1.x += v1 * xv1.x;  acc1.y += v1 * xv1.y;
        acc1.z += v1 * xv1.z;  acc1.w += v1 * xv1.w;
    }

    float4 acc;
    acc.x = acc0.x + acc1.x;
    acc.y = acc0.y + acc1.y;
    acc.z = acc0.z + acc1.z;
    acc.w = acc0.w + acc1.w;

    // reduce across the 4 groups (lanes gl, gl+16, gl+32, gl+48)
#pragma unroll
    for (int off = 16; off < 64; off <<= 1) {
        acc.x += __shfl_xor(acc.x, off, 64);
        acc.y += __shfl_xor(acc.y, off, 64);
        acc.z += __shfl_xor(acc.z, off, 64);
        acc.w += __shfl_xor(acc.w, off, 64);
    }

    if (lane < 16) {
        int o = wid * 16 + gl;
        if (write_y) y4[o] = acc;
        float4 ov = out4[o];
        ov.x = (ov.x + acc.x) * final_scale;
        ov.y = (ov.y + acc.y) * final_scale;
        ov.z = (ov.z + acc.z) * final_scale;
        ov.w = (ov.w + acc.w) * final_scale;
        out4[o] = ov;
    }
}

// ===========================================================================
extern "C" void kernel_launch(void* const* d_in, const int* in_sizes, int n_in,
                              void* d_out, int out_size, void* d_ws, size_t ws_size,
                              hipStream_t stream) {
    const float* user = (const float*)d_in[0];
    const float* item = (const float*)d_in[1];
    const int*   rows = (const int*)d_in[2];
    const int*   cols = (const int*)d_in[3];
    const float* vals = (const float*)d_in[4];
    float* out = (float*)d_out;

    const int nnz = in_sizes[2];
    const size_t nfloats = (size_t)N_NODES * EMBED_DIM;   // 9.6M floats
    const int total4 = (int)(nfloats / 4);
    const int n_user4 = (N_USERS * EMBED_DIM) / 4;

    // ---- workspace layout (256B-aligned regions) ----
    // part[] (64MB) overlays bufA+bufB (76.8MB): dead after P2, before init.
    char* ws = (char*)d_ws;
    size_t off = 0;
    auto alloc = [&](size_t bytes) { size_t p = off; off += (bytes + 255) & ~(size_t)255; return p; };
    size_t o_bufA   = alloc(nfloats * sizeof(float));
    size_t o_bufB   = alloc(nfloats * sizeof(float));
    size_t o_rptr   = alloc((N_NODES + 1) * sizeof(int));
    size_t o_blkcnt = alloc((size_t)NBLK * NB * sizeof(int));    // 2.4 MB
    size_t o_btot   = alloc((NB + 1) * sizeof(int));
    size_t o_bstart = alloc((NB + 1) * sizeof(int));
    size_t o_edges  = alloc(((size_t)nnz + 8) * sizeof(int2));   // 64 MB

    float* bufA   = (float*)(ws + o_bufA);
    float* bufB   = (float*)(ws + o_bufB);
    int* row_ptr  = (int*)(ws + o_rptr);
    int* blk_cnt  = (int*)(ws + o_blkcnt);
    int* bkt_tot  = (int*)(ws + o_btot);
    int* bstart   = (int*)(ws + o_bstart);
    int2* part    = (int2*)(ws + o_bufA);     // overlay on bufA/bufB
    int2* edges   = (int2*)(ws + o_edges);
    (void)ws_size;

    // ---- CSR build: two-level LDS counting sort (zero global atomics) ----
    part_count_kernel<<<NBLK, 256, 0, stream>>>(rows, blk_cnt, nnz);
    scan_blocks_kernel<<<NB, 256, 0, stream>>>(blk_cnt, bkt_tot);
    scan_buckets_kernel<<<1, 256, 0, stream>>>(bkt_tot, bstart, nnz);
    partition_kernel<<<NBLK, 256, 0, stream>>>(rows, cols, vals, blk_cnt, bstart, part, nnz);
    bucket_sort_kernel<<<NB, 256, 0, stream>>>(part, bstart, row_ptr, edges, nnz);

    // ---- init x = out = emb0 (overwrites part overlay; after P2 on stream) ----
    int iblocks = (total4 + 255) / 256;
    init4_kernel<<<iblocks, 256, 0, stream>>>((const float4*)user, (const float4*)item,
                                              (float4*)bufA, (float4*)out, n_user4, total4);

    // ---- 3 fused gather-SpMM layers ----
    float* x = bufA; float* y = bufB;
    int sblocks = (N_NODES * 64 + 255) / 256;   // 1 wave per row
    for (int layer = 0; layer < 3; ++layer) {
        float fs = (layer == 2) ? 0.25f : 1.0f;
        int wy = (layer == 2) ? 0 : 1;
        spmm_csr_kernel<<<sblocks, 256, 0, stream>>>(row_ptr, edges,
                                                     (const float4*)x,
                                                     (float4*)y, (float4*)out, fs, wy);
        float* t = x; x = y; y = t;
    }
}

// Round 14
// 883.840 us; speedup vs baseline: 22.9958x; 1.4065x over previous
//
#include <hip/hip_runtime.h>

#define N_USERS 100000
#define N_ITEMS 50000
#define N_NODES 150000
#define EMBED_DIM 64

#define BUCKET_SHIFT 7                 // 128 rows per bucket
#define NB 1172                        // ceil(150000 / 128)
#define NBLK 512                       // partition blocks (scanA assumes == 2*256)

__device__ inline float4 bf4_to_f4(ushort4 u) {
    float4 f;
    f.x = __uint_as_float((unsigned)u.x << 16);
    f.y = __uint_as_float((unsigned)u.y << 16);
    f.z = __uint_as_float((unsigned)u.z << 16);
    f.w = __uint_as_float((unsigned)u.w << 16);
    return f;
}

__device__ inline unsigned short f_to_bf(float f) {
    unsigned u = __float_as_uint(f);
    return (unsigned short)((u + 0x7FFFu + ((u >> 16) & 1u)) >> 16);   // RNE
}

// ===========================================================================
// init: out = concat(user,item) fp32 ; x_bf = bf16(concat)
// ===========================================================================
__global__ void init_kernel(const float4* __restrict__ user,
                            const float4* __restrict__ item,
                            ushort4* __restrict__ xbf,
                            float4* __restrict__ acc,
                            int n_user4, int total4) {
    int i = blockIdx.x * blockDim.x + threadIdx.x;
    if (i < total4) {
        float4 v = (i < n_user4) ? user[i] : item[i - n_user4];
        acc[i] = v;
        ushort4 b;
        b.x = f_to_bf(v.x); b.y = f_to_bf(v.y);
        b.z = f_to_bf(v.z); b.w = f_to_bf(v.w);
        xbf[i] = b;
    }
}

// ===========================================================================
// P0: per-block LDS histogram over row-buckets (no global atomics)
// ===========================================================================
__global__ __launch_bounds__(256) void part_count_kernel(const int* __restrict__ rows,
                                                         int* __restrict__ blk_cnt, int nnz) {
    __shared__ int cnt[NB];
    for (int i = threadIdx.x; i < NB; i += 256) cnt[i] = 0;
    __syncthreads();
    int b = blockIdx.x;
    int chunk = (nnz + NBLK - 1) / NBLK;
    int s = b * chunk, e = min(nnz, s + chunk);
    for (int i = s + threadIdx.x; i < e; i += 256)
        atomicAdd(&cnt[rows[i] >> BUCKET_SHIFT], 1);
    __syncthreads();
    for (int i = threadIdx.x; i < NB; i += 256) blk_cnt[b * NB + i] = cnt[i];
}

// ===========================================================================
// scanA: per bucket, exclusive scan over NBLK per-block counts; total->bkt_tot
// ===========================================================================
__global__ __launch_bounds__(256) void scan_blocks_kernel(int* __restrict__ blk_cnt,
                                                          int* __restrict__ bkt_tot) {
    __shared__ int lds[256];
    int nb = blockIdx.x, tid = threadIdx.x;
    int v0 = blk_cnt[(2 * tid) * NB + nb];
    int v1 = blk_cnt[(2 * tid + 1) * NB + nb];
    int s = v0 + v1;
    lds[tid] = s; __syncthreads();
    for (int off = 1; off < 256; off <<= 1) {
        int t = (tid >= off) ? lds[tid - off] : 0;
        __syncthreads();
        lds[tid] += t;
        __syncthreads();
    }
    int excl = lds[tid] - s;
    blk_cnt[(2 * tid) * NB + nb] = excl;
    blk_cnt[(2 * tid + 1) * NB + nb] = excl + v0;
    if (tid == 255) bkt_tot[nb] = lds[255];
}

// ===========================================================================
// scanB: exclusive scan over NB bucket totals -> bucket_start[NB+1]
// ===========================================================================
__global__ __launch_bounds__(256) void scan_buckets_kernel(const int* __restrict__ bkt_tot,
                                                           int* __restrict__ bucket_start, int nnz) {
    __shared__ int lds[256];
    int tid = threadIdx.x;
    int v[5]; int s = 0;
#pragma unroll
    for (int j = 0; j < 5; ++j) {
        int idx = tid * 5 + j;
        v[j] = (idx < NB) ? bkt_tot[idx] : 0;
        s += v[j];
    }
    lds[tid] = s; __syncthreads();
    for (int off = 1; off < 256; off <<= 1) {
        int t = (tid >= off) ? lds[tid - off] : 0;
        __syncthreads();
        lds[tid] += t;
        __syncthreads();
    }
    int run = lds[tid] - s;
#pragma unroll
    for (int j = 0; j < 5; ++j) {
        int idx = tid * 5 + j;
        if (idx < NB) bucket_start[idx] = run;
        run += v[j];
    }
    if (tid == 0) bucket_start[NB] = nnz;
}

// ===========================================================================
// P1: partition edges into bucket-ordered array via LDS cursors (no g-atomics)
// part entry: (local_row<<18 | col, val_bits)
// ===========================================================================
__global__ __launch_bounds__(256) void partition_kernel(const int* __restrict__ rows,
                                                        const int* __restrict__ cols,
                                                        const float* __restrict__ vals,
                                                        const int* __restrict__ blk_cnt,
                                                        const int* __restrict__ bucket_start,
                                                        int2* __restrict__ part, int nnz) {
    __shared__ int cur[NB];
    int b = blockIdx.x;
    for (int i = threadIdx.x; i < NB; i += 256)
        cur[i] = bucket_start[i] + blk_cnt[b * NB + i];
    __syncthreads();
    int chunk = (nnz + NBLK - 1) / NBLK;
    int s = b * chunk, e = min(nnz, s + chunk);
    for (int i = s + threadIdx.x; i < e; i += 256) {
        int r = rows[i];
        int nb = r >> BUCKET_SHIFT;
        int rl = r & 127;
        int pos = atomicAdd(&cur[nb], 1);
        part[pos] = make_int2((rl << 18) | cols[i], __float_as_int(vals[i]));
    }
}

// ===========================================================================
// P2: per-bucket fine counting sort -> final CSR edges + row_ptr
// ===========================================================================
__global__ __launch_bounds__(256) void bucket_sort_kernel(const int2* __restrict__ part,
                                                          const int* __restrict__ bucket_start,
                                                          int* __restrict__ row_ptr,
                                                          int2* __restrict__ edges, int nnz) {
    __shared__ int cnt[128];
    __shared__ int off[128];
    int nb = blockIdx.x, tid = threadIdx.x;
    int base = bucket_start[nb];
    int cntE = bucket_start[nb + 1] - base;

    if (tid < 128) cnt[tid] = 0;
    __syncthreads();
    for (int i = tid; i < cntE; i += 256)
        atomicAdd(&cnt[part[base + i].x >> 18], 1);
    __syncthreads();

    if (tid < 128) off[tid] = cnt[tid];
    __syncthreads();
    for (int o = 1; o < 128; o <<= 1) {
        int t = 0;
        if (tid < 128 && tid >= o) t = off[tid - o];
        __syncthreads();
        if (tid < 128) off[tid] += t;
        __syncthreads();
    }
    int r0 = nb << BUCKET_SHIFT;
    if (tid < 128) {
        int excl = off[tid] - cnt[tid];
        off[tid] = excl;
        int r = r0 + tid;
        if (r < N_NODES) row_ptr[r] = base + excl;
    }
    __syncthreads();

    for (int i = tid; i < cntE; i += 256) {
        int2 ev = part[base + i];
        int rl = ev.x >> 18;
        int rank = atomicAdd(&off[rl], 1);
        edges[base + rank] = make_int2(ev.x & 0x3FFFF, ev.y);
    }
    if (nb == 0 && tid == 0) row_ptr[N_NODES] = nnz;
}

// ===========================================================================
// Row-parallel gather SpMM, bf16 x, 8 edges/iter, two accumulator chains.
//   wave = row; 4 groups of 16 lanes; lane gl loads ushort4 chunk gl of
//   x_bf[col]; fp32 accumulate; cross-group shfl_xor reduce; epilogue
//   writes y_bf (bf16, next layer's x) and fp32 out.
// ===========================================================================
__global__ __launch_bounds__(256) void spmm_csr_kernel(
        const int* __restrict__ row_ptr, const int2* __restrict__ edges,
        const ushort4* __restrict__ xbf,
        ushort4* __restrict__ ybf, float4* __restrict__ out4,
        float final_scale, int write_y) {
    int wid = (blockIdx.x * blockDim.x + threadIdx.x) >> 6;   // wave id = row
    int lane = threadIdx.x & 63;
    if (wid >= N_NODES) return;

    int start = row_ptr[wid];
    int nj = row_ptr[wid + 1] - start;
    int g  = lane >> 4;     // group 0..3
    int gl = lane & 15;     // ushort4 chunk of the 64-dim row

    const int2* ep = edges + start;
    float4 acc0 = make_float4(0.f, 0.f, 0.f, 0.f);
    float4 acc1 = make_float4(0.f, 0.f, 0.f, 0.f);

    int jmax = (nj + 7) >> 3;   // 8 edges per iteration
    for (int j = 0; j < jmax; ++j) {
        int i0 = (j << 3) + g;
        int i1 = i0 + 4;
        bool ok0 = i0 < nj;
        bool ok1 = i1 < nj;
        int2 ev0 = ep[ok0 ? i0 : 0];
        int2 ev1 = ep[ok1 ? i1 : 0];
        float v0 = ok0 ? __int_as_float(ev0.y) : 0.0f;
        float v1 = ok1 ? __int_as_float(ev1.y) : 0.0f;
        float4 xv0 = bf4_to_f4(xbf[ev0.x * 16 + gl]);
        float4 xv1 = bf4_to_f4(xbf[ev1.x * 16 + gl]);
        acc0.x += v0 * xv0.x;  acc0.y += v0 * xv0.y;
        acc0.z += v0 * xv0.z;  acc0.w += v0 * xv0.w;
        acc1.x += v1 * xv1.x;  acc1.y += v1 * xv1.y;
        acc1.z += v1 * xv1.z;  acc1.w += v1 * xv1.w;
    }

    float4 acc;
    acc.x = acc0.x + acc1.x;
    acc.y = acc0.y + acc1.y;
    acc.z = acc0.z + acc1.z;
    acc.w = acc0.w + acc1.w;

#pragma unroll
    for (int off = 16; off < 64; off <<= 1) {
        acc.x += __shfl_xor(acc.x, off, 64);
        acc.y += __shfl_xor(acc.y, off, 64);
        acc.z += __shfl_xor(acc.z, off, 64);
        acc.w += __shfl_xor(acc.w, off, 64);
    }

    if (lane < 16) {
        int o = wid * 16 + gl;
        if (write_y) {
            ushort4 b;
            b.x = f_to_bf(acc.x); b.y = f_to_bf(acc.y);
            b.z = f_to_bf(acc.z); b.w = f_to_bf(acc.w);
            ybf[o] = b;
        }
        float4 ov = out4[o];
        ov.x = (ov.x + acc.x) * final_scale;
        ov.y = (ov.y + acc.y) * final_scale;
        ov.z = (ov.z + acc.z) * final_scale;
        ov.w = (ov.w + acc.w) * final_scale;
        out4[o] = ov;
    }
}

// ===========================================================================
extern "C" void kernel_launch(void* const* d_in, const int* in_sizes, int n_in,
                              void* d_out, int out_size, void* d_ws, size_t ws_size,
                              hipStream_t stream) {
    const float* user = (const float*)d_in[0];
    const float* item = (const float*)d_in[1];
    const int*   rows = (const int*)d_in[2];
    const int*   cols = (const int*)d_in[3];
    const float* vals = (const float*)d_in[4];
    float* out = (float*)d_out;

    const int nnz = in_sizes[2];
    const size_t nfloats = (size_t)N_NODES * EMBED_DIM;   // 9.6M
    const int total4 = (int)(nfloats / 4);
    const int n_user4 = (N_USERS * EMBED_DIM) / 4;

    // ---- workspace layout (256B-aligned regions) ----
    // part[] (64MB) is dead after P2; x_bf/y_bf (19.2MB each) overlay it.
    char* ws = (char*)d_ws;
    size_t off = 0;
    auto alloc = [&](size_t bytes) { size_t p = off; off += (bytes + 255) & ~(size_t)255; return p; };
    size_t o_part   = alloc(((size_t)nnz + 8) * sizeof(int2));   // 64 MB
    size_t o_rptr   = alloc((N_NODES + 1) * sizeof(int));
    size_t o_blkcnt = alloc((size_t)NBLK * NB * sizeof(int));    // 2.4 MB
    size_t o_btot   = alloc((NB + 1) * sizeof(int));
    size_t o_bstart = alloc((NB + 1) * sizeof(int));
    size_t o_edges  = alloc(((size_t)nnz + 8) * sizeof(int2));   // 64 MB

    int2* part    = (int2*)(ws + o_part);
    int* row_ptr  = (int*)(ws + o_rptr);
    int* blk_cnt  = (int*)(ws + o_blkcnt);
    int* bkt_tot  = (int*)(ws + o_btot);
    int* bstart   = (int*)(ws + o_bstart);
    int2* edges   = (int2*)(ws + o_edges);
    // bf16 state buffers overlay part (dead after bucket_sort_kernel)
    ushort4* xbf  = (ushort4*)(ws + o_part);
    ushort4* ybf  = (ushort4*)(ws + o_part + (size_t)N_NODES * EMBED_DIM * 2);
    (void)ws_size;

    // ---- CSR build: two-level LDS counting sort (zero global atomics) ----
    part_count_kernel<<<NBLK, 256, 0, stream>>>(rows, blk_cnt, nnz);
    scan_blocks_kernel<<<NB, 256, 0, stream>>>(blk_cnt, bkt_tot);
    scan_buckets_kernel<<<1, 256, 0, stream>>>(bkt_tot, bstart, nnz);
    partition_kernel<<<NBLK, 256, 0, stream>>>(rows, cols, vals, blk_cnt, bstart, part, nnz);
    bucket_sort_kernel<<<NB, 256, 0, stream>>>(part, bstart, row_ptr, edges, nnz);

    // ---- init: out = emb (fp32), x_bf = bf16(emb)  (after P2: part now dead) ----
    int iblocks = (total4 + 255) / 256;
    init_kernel<<<iblocks, 256, 0, stream>>>((const float4*)user, (const float4*)item,
                                             xbf, (float4*)out, n_user4, total4);

    // ---- 3 fused gather-SpMM layers (bf16 state, fp32 accumulate) ----
    ushort4* x = xbf; ushort4* y = ybf;
    int sblocks = (N_NODES * 64 + 255) / 256;   // 1 wave per row
    for (int layer = 0; layer < 3; ++layer) {
        float fs = (layer == 2) ? 0.25f : 1.0f;
        int wy = (layer == 2) ? 0 : 1;
        spmm_csr_kernel<<<sblocks, 256, 0, stream>>>(row_ptr, edges,
                                                     (const ushort4*)x,
                                                     y, (float4*)out, fs, wy);
        ushort4* t = x; x = y; y = t;
    }
}

// Round 15
// 882.023 us; speedup vs baseline: 23.0432x; 1.0021x over previous
//
#include <hip/hip_runtime.h>

#define N_USERS 100000
#define N_ITEMS 50000
#define N_NODES 150000
#define EMBED_DIM 64

#define BUCKET_SHIFT 9                 // 512 rows per bucket
#define BUCKET_ROWS 512
#define NB 293                         // ceil(150000 / 512)
#define NBLK 2048                      // partition blocks (scanA assumes == 8*256)

__device__ inline float4 bf4_to_f4(ushort4 u) {
    float4 f;
    f.x = __uint_as_float((unsigned)u.x << 16);
    f.y = __uint_as_float((unsigned)u.y << 16);
    f.z = __uint_as_float((unsigned)u.z << 16);
    f.w = __uint_as_float((unsigned)u.w << 16);
    return f;
}

__device__ inline unsigned short f_to_bf(float f) {
    unsigned u = __float_as_uint(f);
    return (unsigned short)((u + 0x7FFFu + ((u >> 16) & 1u)) >> 16);   // RNE
}

// ===========================================================================
// init: out = concat(user,item) fp32 ; x_bf = bf16(concat)
// ===========================================================================
__global__ void init_kernel(const float4* __restrict__ user,
                            const float4* __restrict__ item,
                            ushort4* __restrict__ xbf,
                            float4* __restrict__ acc,
                            int n_user4, int total4) {
    int i = blockIdx.x * blockDim.x + threadIdx.x;
    if (i < total4) {
        float4 v = (i < n_user4) ? user[i] : item[i - n_user4];
        acc[i] = v;
        ushort4 b;
        b.x = f_to_bf(v.x); b.y = f_to_bf(v.y);
        b.z = f_to_bf(v.z); b.w = f_to_bf(v.w);
        xbf[i] = b;
    }
}

// ===========================================================================
// P0: per-block LDS histogram over row-buckets (no global atomics)
// ===========================================================================
__global__ __launch_bounds__(256) void part_count_kernel(const int* __restrict__ rows,
                                                         int* __restrict__ blk_cnt, int nnz) {
    __shared__ int cnt[NB];
    for (int i = threadIdx.x; i < NB; i += 256) cnt[i] = 0;
    __syncthreads();
    int b = blockIdx.x;
    int chunk = (nnz + NBLK - 1) / NBLK;
    int s = b * chunk, e = min(nnz, s + chunk);
    for (int i = s + threadIdx.x; i < e; i += 256)
        atomicAdd(&cnt[rows[i] >> BUCKET_SHIFT], 1);
    __syncthreads();
    for (int i = threadIdx.x; i < NB; i += 256) blk_cnt[b * NB + i] = cnt[i];
}

// ===========================================================================
// scanA: per bucket, exclusive scan over NBLK per-block counts (8 per thread);
// bucket total -> bkt_tot. One block per bucket.
// ===========================================================================
__global__ __launch_bounds__(256) void scan_blocks_kernel(int* __restrict__ blk_cnt,
                                                          int* __restrict__ bkt_tot) {
    __shared__ int psum[256];
    int nb = blockIdx.x, tid = threadIdx.x;
    int v[8]; int s = 0;
#pragma unroll
    for (int j = 0; j < 8; ++j) {
        v[j] = blk_cnt[(8 * tid + j) * NB + nb];
        s += v[j];
    }
    psum[tid] = s; __syncthreads();
    for (int off = 1; off < 256; off <<= 1) {
        int t = (tid >= off) ? psum[tid - off] : 0;
        __syncthreads();
        psum[tid] += t;
        __syncthreads();
    }
    int run = psum[tid] - s;
#pragma unroll
    for (int j = 0; j < 8; ++j) {
        blk_cnt[(8 * tid + j) * NB + nb] = run;
        run += v[j];
    }
    if (tid == 255) bkt_tot[nb] = psum[255];
}

// ===========================================================================
// scanB: exclusive scan over NB bucket totals -> bucket_start[NB+1]
// ===========================================================================
__global__ __launch_bounds__(256) void scan_buckets_kernel(const int* __restrict__ bkt_tot,
                                                           int* __restrict__ bucket_start, int nnz) {
    __shared__ int lds[256];
    int tid = threadIdx.x;
    int v[2]; int s = 0;
#pragma unroll
    for (int j = 0; j < 2; ++j) {
        int idx = tid * 2 + j;
        v[j] = (idx < NB) ? bkt_tot[idx] : 0;
        s += v[j];
    }
    lds[tid] = s; __syncthreads();
    for (int off = 1; off < 256; off <<= 1) {
        int t = (tid >= off) ? lds[tid - off] : 0;
        __syncthreads();
        lds[tid] += t;
        __syncthreads();
    }
    int run = lds[tid] - s;
#pragma unroll
    for (int j = 0; j < 2; ++j) {
        int idx = tid * 2 + j;
        if (idx < NB) bucket_start[idx] = run;
        run += v[j];
    }
    if (tid == 0) bucket_start[NB] = nnz;
}

// ===========================================================================
// P1: partition edges into bucket-ordered array via LDS cursors (no g-atomics)
// part entry: (local_row<<18 | col, val_bits)   local_row < 512, col < 2^18
// ===========================================================================
__global__ __launch_bounds__(256) void partition_kernel(const int* __restrict__ rows,
                                                        const int* __restrict__ cols,
                                                        const float* __restrict__ vals,
                                                        const int* __restrict__ blk_cnt,
                                                        const int* __restrict__ bucket_start,
                                                        int2* __restrict__ part, int nnz) {
    __shared__ int cur[NB];
    int b = blockIdx.x;
    for (int i = threadIdx.x; i < NB; i += 256)
        cur[i] = bucket_start[i] + blk_cnt[b * NB + i];
    __syncthreads();
    int chunk = (nnz + NBLK - 1) / NBLK;
    int s = b * chunk, e = min(nnz, s + chunk);
    for (int i = s + threadIdx.x; i < e; i += 256) {
        int r = rows[i];
        int nb = r >> BUCKET_SHIFT;
        int rl = r & (BUCKET_ROWS - 1);
        int pos = atomicAdd(&cur[nb], 1);
        part[pos] = make_int2((rl << 18) | cols[i], __float_as_int(vals[i]));
    }
}

// ===========================================================================
// P2: per-bucket fine counting sort (512 rows in LDS) -> final CSR edges
// + row_ptr emitted directly.
// ===========================================================================
__global__ __launch_bounds__(256) void bucket_sort_kernel(const int2* __restrict__ part,
                                                          const int* __restrict__ bucket_start,
                                                          int* __restrict__ row_ptr,
                                                          int2* __restrict__ edges, int nnz) {
    __shared__ int cnt[BUCKET_ROWS];
    __shared__ int off[BUCKET_ROWS];
    __shared__ int psum[256];
    int nb = blockIdx.x, tid = threadIdx.x;
    int base = bucket_start[nb];
    int cntE = bucket_start[nb + 1] - base;

    cnt[tid] = 0; cnt[tid + 256] = 0;
    __syncthreads();
    for (int i = tid; i < cntE; i += 256)
        atomicAdd(&cnt[part[base + i].x >> 18], 1);
    __syncthreads();

    // exclusive scan over 512 counts: 2 per thread
    int c0 = cnt[2 * tid], c1 = cnt[2 * tid + 1];
    int s = c0 + c1;
    psum[tid] = s; __syncthreads();
    for (int o = 1; o < 256; o <<= 1) {
        int t = (tid >= o) ? psum[tid - o] : 0;
        __syncthreads();
        psum[tid] += t;
        __syncthreads();
    }
    int excl = psum[tid] - s;
    off[2 * tid] = excl;
    off[2 * tid + 1] = excl + c0;

    int r0 = nb << BUCKET_SHIFT;
    int ra = r0 + 2 * tid, rb = r0 + 2 * tid + 1;
    if (ra < N_NODES) row_ptr[ra] = base + excl;
    if (rb < N_NODES) row_ptr[rb] = base + excl + c0;
    __syncthreads();

    for (int i = tid; i < cntE; i += 256) {
        int2 ev = part[base + i];
        int rl = ev.x >> 18;
        int rank = atomicAdd(&off[rl], 1);
        edges[base + rank] = make_int2(ev.x & 0x3FFFF, ev.y);
    }
    if (nb == 0 && tid == 0) row_ptr[N_NODES] = nnz;
}

// ===========================================================================
// Row-parallel gather SpMM, bf16 x, 8 edges/iter, two accumulator chains.
// ===========================================================================
__global__ __launch_bounds__(256) void spmm_csr_kernel(
        const int* __restrict__ row_ptr, const int2* __restrict__ edges,
        const ushort4* __restrict__ xbf,
        ushort4* __restrict__ ybf, float4* __restrict__ out4,
        float final_scale, int write_y) {
    int wid = (blockIdx.x * blockDim.x + threadIdx.x) >> 6;   // wave id = row
    int lane = threadIdx.x & 63;
    if (wid >= N_NODES) return;

    int start = row_ptr[wid];
    int nj = row_ptr[wid + 1] - start;
    int g  = lane >> 4;     // group 0..3
    int gl = lane & 15;     // ushort4 chunk of the 64-dim row

    const int2* ep = edges + start;
    float4 acc0 = make_float4(0.f, 0.f, 0.f, 0.f);
    float4 acc1 = make_float4(0.f, 0.f, 0.f, 0.f);

    int jmax = (nj + 7) >> 3;   // 8 edges per iteration
    for (int j = 0; j < jmax; ++j) {
        int i0 = (j << 3) + g;
        int i1 = i0 + 4;
        bool ok0 = i0 < nj;
        bool ok1 = i1 < nj;
        int2 ev0 = ep[ok0 ? i0 : 0];
        int2 ev1 = ep[ok1 ? i1 : 0];
        float v0 = ok0 ? __int_as_float(ev0.y) : 0.0f;
        float v1 = ok1 ? __int_as_float(ev1.y) : 0.0f;
        float4 xv0 = bf4_to_f4(xbf[ev0.x * 16 + gl]);
        float4 xv1 = bf4_to_f4(xbf[ev1.x * 16 + gl]);
        acc0.x += v0 * xv0.x;  acc0.y += v0 * xv0.y;
        acc0.z += v0 * xv0.z;  acc0.w += v0 * xv0.w;
        acc1.x += v1 * xv1.x;  acc1.y += v1 * xv1.y;
        acc1.z += v1 * xv1.z;  acc1.w += v1 * xv1.w;
    }

    float4 acc;
    acc.x = acc0.x + acc1.x;
    acc.y = acc0.y + acc1.y;
    acc.z = acc0.z + acc1.z;
    acc.w = acc0.w + acc1.w;

#pragma unroll
    for (int off = 16; off < 64; off <<= 1) {
        acc.x += __shfl_xor(acc.x, off, 64);
        acc.y += __shfl_xor(acc.y, off, 64);
        acc.z += __shfl_xor(acc.z, off, 64);
        acc.w += __shfl_xor(acc.w, off, 64);
    }

    if (lane < 16) {
        int o = wid * 16 + gl;
        if (write_y) {
            ushort4 b;
            b.x = f_to_bf(acc.x); b.y = f_to_bf(acc.y);
            b.z = f_to_bf(acc.z); b.w = f_to_bf(acc.w);
            ybf[o] = b;
        }
        float4 ov = out4[o];
        ov.x = (ov.x + acc.x) * final_scale;
        ov.y = (ov.y + acc.y) * final_scale;
        ov.z = (ov.z + acc.z) * final_scale;
        ov.w = (ov.w + acc.w) * final_scale;
        out4[o] = ov;
    }
}

// ===========================================================================
extern "C" void kernel_launch(void* const* d_in, const int* in_sizes, int n_in,
                              void* d_out, int out_size, void* d_ws, size_t ws_size,
                              hipStream_t stream) {
    const float* user = (const float*)d_in[0];
    const float* item = (const float*)d_in[1];
    const int*   rows = (const int*)d_in[2];
    const int*   cols = (const int*)d_in[3];
    const float* vals = (const float*)d_in[4];
    float* out = (float*)d_out;

    const int nnz = in_sizes[2];
    const size_t nfloats = (size_t)N_NODES * EMBED_DIM;   // 9.6M
    const int total4 = (int)(nfloats / 4);
    const int n_user4 = (N_USERS * EMBED_DIM) / 4;

    // ---- workspace layout (256B-aligned regions) ----
    // part[] (64MB) is dead after P2; x_bf/y_bf (19.2MB each) overlay it.
    char* ws = (char*)d_ws;
    size_t off = 0;
    auto alloc = [&](size_t bytes) { size_t p = off; off += (bytes + 255) & ~(size_t)255; return p; };
    size_t o_part   = alloc(((size_t)nnz + 8) * sizeof(int2));   // 64 MB
    size_t o_rptr   = alloc((N_NODES + 1) * sizeof(int));
    size_t o_blkcnt = alloc((size_t)NBLK * NB * sizeof(int));    // 2.4 MB
    size_t o_btot   = alloc((NB + 1) * sizeof(int));
    size_t o_bstart = alloc((NB + 1) * sizeof(int));
    size_t o_edges  = alloc(((size_t)nnz + 8) * sizeof(int2));   // 64 MB

    int2* part    = (int2*)(ws + o_part);
    int* row_ptr  = (int*)(ws + o_rptr);
    int* blk_cnt  = (int*)(ws + o_blkcnt);
    int* bkt_tot  = (int*)(ws + o_btot);
    int* bstart   = (int*)(ws + o_bstart);
    int2* edges   = (int2*)(ws + o_edges);
    // bf16 state buffers overlay part (dead after bucket_sort_kernel)
    ushort4* xbf  = (ushort4*)(ws + o_part);
    ushort4* ybf  = (ushort4*)(ws + o_part + (size_t)N_NODES * EMBED_DIM * 2);
    (void)ws_size;

    // ---- CSR build: two-level LDS counting sort (zero global atomics) ----
    part_count_kernel<<<NBLK, 256, 0, stream>>>(rows, blk_cnt, nnz);
    scan_blocks_kernel<<<NB, 256, 0, stream>>>(blk_cnt, bkt_tot);
    scan_buckets_kernel<<<1, 256, 0, stream>>>(bkt_tot, bstart, nnz);
    partition_kernel<<<NBLK, 256, 0, stream>>>(rows, cols, vals, blk_cnt, bstart, part, nnz);
    bucket_sort_kernel<<<NB, 256, 0, stream>>>(part, bstart, row_ptr, edges, nnz);

    // ---- init: out = emb (fp32), x_bf = bf16(emb)  (after P2: part now dead) ----
    int iblocks = (total4 + 255) / 256;
    init_kernel<<<iblocks, 256, 0, stream>>>((const float4*)user, (const float4*)item,
                                             xbf, (float4*)out, n_user4, total4);

    // ---- 3 fused gather-SpMM layers (bf16 state, fp32 accumulate) ----
    ushort4* x = xbf; ushort4* y = ybf;
    int sblocks = (N_NODES * 64 + 255) / 256;   // 1 wave per row
    for (int layer = 0; layer < 3; ++layer) {
        float fs = (layer == 2) ? 0.25f : 1.0f;
        int wy = (layer == 2) ? 0 : 1;
        spmm_csr_kernel<<<sblocks, 256, 0, stream>>>(row_ptr, edges,
                                                     (const ushort4*)x,
                                                     y, (float4*)out, fs, wy);
        ushort4* t = x; x = y; y = t;
    }
}